// Round 1
// baseline (158.609 us; speedup 1.0000x reference)
//
#include <hip/hip_runtime.h>

#define BPC 32  // blocks per cluster in mstep

__global__ void zero_k(int* __restrict__ p, int n) {
  int i = blockIdx.x * blockDim.x + threadIdx.x;
  if (i < n) p[i] = 0;
}

__global__ __launch_bounds__(256) void assign_k(
    const float* __restrict__ r, const float* __restrict__ ri,
    int* __restrict__ z, float* __restrict__ pig, int* __restrict__ counts, int n)
{
  __shared__ float lpi[256][33];
  __shared__ int hist[16];
  float acc[32];
#pragma unroll
  for (int c = 0; c < 32; ++c) acc[c] = 0.f;
  if (threadIdx.x < 16) hist[threadIdx.x] = 0;
  __syncthreads();

  for (int i = blockIdx.x * blockDim.x + threadIdx.x; i < n;
       i += gridDim.x * blockDim.x) {
    const float4* rr = (const float4*)(r + (size_t)i * 16);
    float4 a0 = rr[0], a1 = rr[1], a2 = rr[2], a3 = rr[3];
    float best = a0.x; int zi = 0;
#define CHK(v, c) if ((v) > best) { best = (v); zi = (c); }
    CHK(a0.y,1) CHK(a0.z,2) CHK(a0.w,3)
    CHK(a1.x,4) CHK(a1.y,5) CHK(a1.z,6) CHK(a1.w,7)
    CHK(a2.x,8) CHK(a2.y,9) CHK(a2.z,10) CHK(a2.w,11)
    CHK(a3.x,12) CHK(a3.y,13) CHK(a3.z,14) CHK(a3.w,15)
#undef CHK
    z[i] = zi;
    atomicAdd(&hist[zi], 1);
    const float4* qq = (const float4*)(ri + (size_t)i * 32);
#pragma unroll
    for (int q = 0; q < 8; ++q) {
      float4 v = qq[q];
      acc[4*q+0] += v.x; acc[4*q+1] += v.y;
      acc[4*q+2] += v.z; acc[4*q+3] += v.w;
    }
  }

#pragma unroll
  for (int c = 0; c < 32; ++c) lpi[threadIdx.x][c] = acc[c];
  __syncthreads();
  if (threadIdx.x < 32) {
    float s = 0.f;
    for (int t = 0; t < 256; ++t) s += lpi[t][threadIdx.x];
    atomicAdd(&pig[threadIdx.x], s);
  }
  if (threadIdx.x < 16) atomicAdd(&counts[threadIdx.x], hist[threadIdx.x]);
}

__global__ void offsets_k(const int* __restrict__ counts,
                          int* __restrict__ offsets, int* __restrict__ cursors) {
  if (threadIdx.x == 0 && blockIdx.x == 0) {
    int run = 0;
    for (int k = 0; k < 16; ++k) {
      offsets[k] = run; cursors[k] = run; run += counts[k];
    }
  }
}

__global__ __launch_bounds__(256) void scatter_k(
    const int* __restrict__ z, int* __restrict__ cursors,
    int* __restrict__ bucket, int n)
{
  __shared__ int h[16];
  __shared__ int base[16];
  int i = blockIdx.x * 256 + threadIdx.x;
  if (threadIdx.x < 16) h[threadIdx.x] = 0;
  __syncthreads();
  int zi = 0, rank = 0;
  bool valid = (i < n);
  if (valid) { zi = z[i]; rank = atomicAdd(&h[zi], 1); }
  __syncthreads();
  if (threadIdx.x < 16 && h[threadIdx.x] > 0)
    base[threadIdx.x] = atomicAdd(&cursors[threadIdx.x], h[threadIdx.x]);
  __syncthreads();
  if (valid) bucket[base[zi] + rank] = i;
}

__global__ __launch_bounds__(256) void mstep_k(
    const float* __restrict__ X, const float* __restrict__ ri,
    const int* __restrict__ bucket, const int* __restrict__ offsets,
    const int* __restrict__ counts,
    float* __restrict__ musg, float* __restrict__ m2g, float* __restrict__ denomg)
{
  const int k = blockIdx.x / BPC;
  const int b = blockIdx.x % BPC;
  const int t = threadIdx.x;
  const int w = t >> 6;
  const int l = t & 63;
  const int g1 = l >> 3;   // d1 group: rows g1*4 .. g1*4+3
  const int g2 = l & 7;    // d2 group: cols g2*4 .. g2*4+3
  const int start = offsets[k];
  const int cnt = counts[k];
  const int wid = b * 4 + w;           // 0..BPC*4-1

  float acc0[4][4] = {{0.f}}, acc1[4][4] = {{0.f}};
  float m0[4] = {0.f, 0.f, 0.f, 0.f};
  float m1[4] = {0.f, 0.f, 0.f, 0.f};
  float dn0 = 0.f, dn1 = 0.f;

  auto body = [&](int ii) {
    const float* xr = X + (size_t)ii * 32;
    float4 x1 = *(const float4*)(xr + g1 * 4);
    float4 x2 = *(const float4*)(xr + g2 * 4);
    float2 wv = *(const float2*)(ri + (size_t)ii * 32 + 2 * k);
    float w0 = wv.x, w1 = wv.y;
    float xv1[4] = {x1.x, x1.y, x1.z, x1.w};
    float xv2[4] = {x2.x, x2.y, x2.z, x2.w};
#pragma unroll
    for (int j = 0; j < 4; ++j) { m0[j] += w0 * xv2[j]; m1[j] += w1 * xv2[j]; }
#pragma unroll
    for (int i1 = 0; i1 < 4; ++i1) {
      float a0 = w0 * xv1[i1], a1 = w1 * xv1[i1];
#pragma unroll
      for (int i2 = 0; i2 < 4; ++i2) {
        acc0[i1][i2] += a0 * xv2[i2];
        acc1[i1][i2] += a1 * xv2[i2];
      }
    }
    dn0 += w0; dn1 += w1;
  };

  for (int base = wid * 64; base < cnt; base += BPC * 4 * 64) {
    int rem = cnt - base; if (rem > 64) rem = 64;
    int idx = 0;
    if (l < rem) idx = bucket[start + base + l];
    if (rem == 64) {
#pragma unroll 4
      for (int p = 0; p < 64; ++p) {
        int ii = __shfl(idx, p, 64);
        body(ii);
      }
    } else {
      for (int p = 0; p < rem; ++p) {
        int ii = __shfl(idx, p, 64);
        body(ii);
      }
    }
  }

  // block-level merge: 4 waves -> 1, then global atomics
  __shared__ float red[4][2048];
#pragma unroll
  for (int i1 = 0; i1 < 4; ++i1)
#pragma unroll
    for (int i2 = 0; i2 < 4; ++i2) {
      int d1 = g1 * 4 + i1, d2 = g2 * 4 + i2;
      red[w][d1 * 32 + d2] = acc0[i1][i2];
      red[w][1024 + d1 * 32 + d2] = acc1[i1][i2];
    }
  __syncthreads();
  for (int q = t; q < 2048; q += 256) {
    float s = red[0][q] + red[1][q] + red[2][q] + red[3][q];
    atomicAdd(&m2g[(size_t)(2 * k + (q >> 10)) * 1024 + (q & 1023)], s);
  }
  if (g1 == 0) {  // one copy of the (redundantly computed) mus partials per wave
#pragma unroll
    for (int j = 0; j < 4; ++j) {
      atomicAdd(&musg[(2 * k) * 32 + g2 * 4 + j], m0[j]);
      atomicAdd(&musg[(2 * k + 1) * 32 + g2 * 4 + j], m1[j]);
    }
  }
  if (l == 0) {
    atomicAdd(&denomg[2 * k], dn0);
    atomicAdd(&denomg[2 * k + 1], dn1);
  }
}

__global__ __launch_bounds__(256) void finalize_k(
    const float* __restrict__ pig, const float* __restrict__ denomg,
    const float* __restrict__ musg, const float* __restrict__ m2g,
    float* __restrict__ out, int n)
{
  const int c = blockIdx.x;   // component 0..31
  const int t = threadIdx.x;
  __shared__ float mu[32];
  float safe = fmaxf(denomg[c], 1e-10f);
  if (t < 32) {
    float m = musg[c * 32 + t] / safe;
    mu[t] = m;
    out[32 + c * 32 + t] = m;          // mus
  }
  if (c == 0 && t < 32) out[t] = pig[t] / (float)n;  // pi
  __syncthreads();
#pragma unroll
  for (int q = 0; q < 4; ++q) {
    int e = t * 4 + q;                  // 0..1023
    int d1 = e >> 5, d2 = e & 31;
    out[32 + 1024 + c * 1024 + e] =
        m2g[c * 1024 + e] / safe - mu[d1] * mu[d2];  // covs
  }
}

extern "C" void kernel_launch(void* const* d_in, const int* in_sizes, int n_in,
                              void* d_out, int out_size, void* d_ws, size_t ws_size,
                              hipStream_t stream) {
  const float* X  = (const float*)d_in[0];
  const float* r  = (const float*)d_in[1];
  const float* ri = (const float*)d_in[2];
  float* out = (float*)d_out;
  const int n = in_sizes[0] / 32;

  // ws layout
  int* z       = (int*)d_ws;
  int* bucket  = z + n;
  int* counts  = bucket + n;
  int* offsets = counts + 16;
  int* cursors = offsets + 16;
  float* pig    = (float*)(cursors + 16);
  float* denomg = pig + 32;
  float* musg   = denomg + 32;
  float* m2g    = musg + 1024;

  const int zero_words = 48 + 32 + 32 + 1024 + 32768;  // counts..m2 inclusive
  zero_k<<<(zero_words + 255) / 256, 256, 0, stream>>>(counts, zero_words);
  assign_k<<<1024, 256, 0, stream>>>(r, ri, z, pig, counts, n);
  offsets_k<<<1, 64, 0, stream>>>(counts, offsets, cursors);
  scatter_k<<<(n + 255) / 256, 256, 0, stream>>>(z, cursors, bucket, n);
  mstep_k<<<16 * BPC, 256, 0, stream>>>(X, ri, bucket, offsets, counts,
                                        musg, m2g, denomg);
  finalize_k<<<32, 256, 0, stream>>>(pig, denomg, musg, m2g, out, n);
}